// Round 1
// baseline (111.601 us; speedup 1.0000x reference)
//
#include <hip/hip_runtime.h>
#include <hip/hip_bf16.h>

// ExpertLinear: y[b,o] = sum_k ew[b,k] * (W[k,o,:].x[b,:] + bias[k,o])
// B=512, E=8, IN=OUT=1024.  Strategy: Z = X @ Wflat^T via bf16 MFMA, then blend.

#define BDIM 512
#define EDIM 8
#define INDIM 1024
#define OUTDIM 1024
#define NDIM (EDIM * OUTDIM) // 8192

typedef __attribute__((ext_vector_type(8))) short frag8;   // 8 bf16 = 4 VGPRs
typedef __attribute__((ext_vector_type(4))) float f32x4;   // MFMA C/D

__device__ inline void async_ld16(void* lds, const void* g) {
  __builtin_amdgcn_global_load_lds(
      (const __attribute__((address_space(1))) void*)g,
      (__attribute__((address_space(3))) void*)lds, 16, 0, 0);
}

__device__ inline ushort f2bf(float f) {
  unsigned u = __builtin_bit_cast(unsigned, f);
  u += 0x7fffu + ((u >> 16) & 1u);   // round-to-nearest-even
  return (ushort)(u >> 16);
}

// ---- pass 1: convert W (8M fp32) and x (512K fp32) to bf16 in workspace ----
__global__ __launch_bounds__(256) void prep_kernel(
    const float* __restrict__ W, const float* __restrict__ x,
    ushort* __restrict__ wsW, ushort* __restrict__ wsX) {
  const int NW = EDIM * OUTDIM * INDIM / 4; // 2097152 float4 groups
  int i = blockIdx.x * 256 + threadIdx.x;   // grid sized exactly NW+NX groups
  const float4* src;
  ushort* dst;
  if (i < NW) {
    src = (const float4*)W + i;
    dst = wsW + (size_t)i * 4;
  } else {
    int j = i - NW;
    src = (const float4*)x + j;
    dst = wsX + (size_t)j * 4;
  }
  float4 v = *src;
  ushort4 o;
  o.x = f2bf(v.x); o.y = f2bf(v.y); o.z = f2bf(v.z); o.w = f2bf(v.w);
  *(ushort4*)dst = o;
}

// ---- pass 2: Z[512][8192] = Xbf16 @ Wbf16^T  (both stored [row][K] row-major)
// m97 structure: 128x128 block tile, BK=64, 4 waves (2x2), each wave 64x64 via
// 4x4 grid of 16x16x32 bf16 MFMA.  global_load_lds width-16 staging.
#define TM 128
#define TN 128
#define BK 64

__global__ __launch_bounds__(256) void gemm_bt(
    const ushort* __restrict__ A,   // Xbf16 [512][1024]
    const ushort* __restrict__ Bm,  // Wbf16 [8192][1024]
    float* __restrict__ Z) {        // [512][8192]
  __shared__ __align__(16) ushort As[TM * BK];
  __shared__ __align__(16) ushort Bs[TN * BK];

  const int tid  = threadIdx.x;
  const int lane = tid & 63;
  const int wave = tid >> 6;
  const int n0 = blockIdx.x * TN;
  const int m0 = blockIdx.y * TM;

  const int wr   = (wave >> 1) * 64;  // wave row offset in tile
  const int wc   = (wave & 1) * 64;   // wave col offset in tile
  const int l15  = lane & 15;
  const int quad = lane >> 4;

  // staging geometry: chunk = 8 rows x 64 cols bf16 = 1KB; lane -> (row, 16B slot)
  const int srow  = lane >> 3;        // row within chunk
  const int selem = (lane & 7) * 8;   // element offset within row (16B)

  f32x4 acc[4][4] = {};

  for (int k0 = 0; k0 < INDIM; k0 += BK) {
#pragma unroll
    for (int c = 0; c < 4; ++c) {
      const int chunk = wave * 4 + c;            // wave-uniform
      const int row = chunk * 8 + srow;
      async_ld16(&As[chunk * 512],
                 A + (size_t)(m0 + row) * INDIM + k0 + selem);
      async_ld16(&Bs[chunk * 512],
                 Bm + (size_t)(n0 + row) * INDIM + k0 + selem);
    }
    __syncthreads();   // drains vmcnt (global_load_lds) + lgkm before use

#pragma unroll
    for (int kk = 0; kk < BK; kk += 32) {
      frag8 a[4], b[4];
#pragma unroll
      for (int i = 0; i < 4; ++i) {
        a[i] = *(const frag8*)&As[(wr + i * 16 + l15) * BK + kk + quad * 8];
        b[i] = *(const frag8*)&Bs[(wc + i * 16 + l15) * BK + kk + quad * 8];
      }
#pragma unroll
      for (int i = 0; i < 4; ++i)
#pragma unroll
        for (int j = 0; j < 4; ++j)
          acc[i][j] = __builtin_amdgcn_mfma_f32_16x16x32_bf16(a[i], b[j], acc[i][j], 0, 0, 0);
    }
    __syncthreads();   // all waves done reading LDS before next stage
  }

  // C/D layout (m89-verified): col = lane&15, row = (lane>>4)*4 + reg
#pragma unroll
  for (int i = 0; i < 4; ++i) {
    const int mrow = m0 + wr + i * 16 + quad * 4;
#pragma unroll
    for (int j = 0; j < 4; ++j) {
      const int ncol = n0 + wc + j * 16 + l15;
#pragma unroll
      for (int r = 0; r < 4; ++r)
        Z[(size_t)(mrow + r) * NDIM + ncol] = acc[i][j][r];
    }
  }
}

// ---- pass 3: y[b,o] = sum_k ew[b,k] * (Z[b, k*1024+o] + bias[k,o]) ----
__global__ __launch_bounds__(256) void blend_kernel(
    const float* __restrict__ Z, const float* __restrict__ ew,
    const float* __restrict__ bias, float* __restrict__ out) {
  int idx = blockIdx.x * 256 + threadIdx.x;  // 524288 total
  int b = idx >> 10;
  int o = idx & 1023;
  const float* zb = Z + (size_t)b * NDIM + o;
  float y = 0.f;
#pragma unroll
  for (int k = 0; k < EDIM; ++k)
    y += ew[b * EDIM + k] * (zb[k * OUTDIM] + bias[k * OUTDIM + o]);
  out[idx] = y;
}

// ---- fallback (ws too small): naive fp32, correct but slow ----
__global__ __launch_bounds__(256) void fallback_kernel(
    const float* __restrict__ x, const float* __restrict__ ew,
    const float* __restrict__ W, const float* __restrict__ bias,
    float* __restrict__ out) {
  int idx = blockIdx.x * 256 + threadIdx.x;
  int b = idx >> 10;
  int o = idx & 1023;
  float y = 0.f;
  for (int k = 0; k < EDIM; ++k) {
    const float* wr = W + ((size_t)k * OUTDIM + o) * INDIM;
    const float* xr = x + (size_t)b * INDIM;
    float dot = 0.f;
    for (int i = 0; i < INDIM; ++i) dot += wr[i] * xr[i];
    y += ew[b * EDIM + k] * (dot + bias[k * OUTDIM + o]);
  }
  out[idx] = y;
}

extern "C" void kernel_launch(void* const* d_in, const int* in_sizes, int n_in,
                              void* d_out, int out_size, void* d_ws, size_t ws_size,
                              hipStream_t stream) {
  const float* x    = (const float*)d_in[0];  // [512][1024]
  const float* ew   = (const float*)d_in[1];  // [512][8]
  const float* W    = (const float*)d_in[2];  // [8][1024][1024]
  const float* bias = (const float*)d_in[3];  // [8][1024]
  float* out = (float*)d_out;                 // [512][1024]

  const size_t offW = 0;                       // 16 MB  bf16 weights
  const size_t offX = (size_t)16 << 20;        //  1 MB  bf16 x
  const size_t offZ = (size_t)17 << 20;        // 16 MB  fp32 Z
  const size_t need = (size_t)33 << 20;

  if (ws_size < need) {
    fallback_kernel<<<2048, 256, 0, stream>>>(x, ew, W, bias, out);
    return;
  }

  char* ws = (char*)d_ws;
  ushort* wsW = (ushort*)(ws + offW);
  ushort* wsX = (ushort*)(ws + offX);
  float*  wsZ = (float*)(ws + offZ);

  // 2097152 + 131072 float4 groups = 8704 blocks exactly
  prep_kernel<<<8704, 256, 0, stream>>>(W, x, wsW, wsX);
  gemm_bt<<<dim3(64, 4), 256, 0, stream>>>(wsX, wsW, wsZ);
  blend_kernel<<<2048, 256, 0, stream>>>(wsZ, ew, bias, out);
}

// Round 2
// 100.405 us; speedup vs baseline: 1.1115x; 1.1115x over previous
//
#include <hip/hip_runtime.h>
#include <hip/hip_bf16.h>

// ExpertLinear fused single kernel.
// y[b,o] = sum_k ew[b,k] * (W[k,o,:].x[b,:] + bias[k,o]),  B=512,E=8,IN=OUT=1024
//
// One block computes a 128(batch) x [16 out-cols x 8 experts] tile:
//   B-matrix tile row n (0..127)  <->  W row  (n>>4)*1024 + o0 + (n&15)
// so MFMA fragment j == expert j and lane&15 == out-col: the expert blend is a
// per-lane epilogue FMA. No workspace, no prep pass, no Z round-trip.
// fp32 -> bf16 conversion happens in-register during LDS staging.
// LDS rows padded to 72 ushorts: frag ds_read_b128 is ~2-way (free) instead of
// the 16-way conflict of the unpadded m97 layout.

#define EDIM 8
#define INDIM 1024
#define OUTDIM 1024
#define TM 128      // batch rows per block
#define ON 16       // out-cols per block (x8 experts = 128 B-rows)
#define TN 128
#define BK 64
#define LDP 72      // padded LDS row stride in ushorts (144 B = 16B-aligned)

typedef __attribute__((ext_vector_type(8))) short frag8;   // 8 bf16 (4 VGPRs)
typedef __attribute__((ext_vector_type(4))) float f32x4;   // MFMA C/D

__device__ inline ushort f2bf(float f) {
  unsigned u = __builtin_bit_cast(unsigned, f);
  u += 0x7fffu + ((u >> 16) & 1u);   // round-to-nearest-even
  return (ushort)(u >> 16);
}

__device__ inline ushort4 f4_to_bf4(float4 v) {
  ushort4 o;
  o.x = f2bf(v.x); o.y = f2bf(v.y); o.z = f2bf(v.z); o.w = f2bf(v.w);
  return o;
}

__global__ __launch_bounds__(512) void expert_linear_fused(
    const float* __restrict__ x,     // [512][1024]
    const float* __restrict__ ew,    // [512][8]
    const float* __restrict__ W,     // [8][1024][1024]
    const float* __restrict__ bias,  // [8][1024]
    float* __restrict__ out) {       // [512][1024]
  __shared__ __align__(16) ushort As[TM * LDP];  // 18432 B
  __shared__ __align__(16) ushort Bs[TN * LDP];  // 18432 B

  const int tid  = threadIdx.x;
  const int lane = tid & 63;
  const int wave = tid >> 6;          // 0..7
  const int o0 = blockIdx.x * ON;     // 0..1008
  const int m0 = blockIdx.y * TM;     // 0..384

  const int l15  = lane & 15;
  const int quad = lane >> 4;

  // ---- staging geometry: thread -> (row, 16B float4 slot), 4 row-passes ----
  const int slot = tid & 15;          // float4 slot within a 64-float row
  const int srow = tid >> 4;          // 0..31; passes add 32

  const float* aptr[4];
  const float* bptr[4];
  ushort* awr[4];
  ushort* bwr[4];
#pragma unroll
  for (int p = 0; p < 4; ++p) {
    const int ar = srow + 32 * p;                      // 0..127 batch-tile row
    aptr[p] = x + (size_t)(m0 + ar) * INDIM + slot * 4;
    awr[p]  = &As[ar * LDP + slot * 4];
    const int br = srow + 32 * p;                      // 0..127 B-tile row
    const int wrow = (br >> 4) * 1024 + o0 + (br & 15); // W flat row (k*1024+o)
    bptr[p] = W + (size_t)wrow * INDIM + slot * 4;
    bwr[p]  = &Bs[br * LDP + slot * 4];
  }

  // ---- fragment read bases ----
  const ushort* ard = &As[(wave * 16 + l15) * LDP + quad * 8];
  const ushort* brd[8];
#pragma unroll
  for (int j = 0; j < 8; ++j)
    brd[j] = &Bs[(j * 16 + l15) * LDP + quad * 8];

  f32x4 acc[8] = {};

  // prefetch iter 0
  float4 pa[4], pb[4];
#pragma unroll
  for (int p = 0; p < 4; ++p) {
    pa[p] = *(const float4*)aptr[p];
    pb[p] = *(const float4*)bptr[p];
  }

  for (int it = 0; it < INDIM / BK; ++it) {
    // convert + stage current tile
#pragma unroll
    for (int p = 0; p < 4; ++p) {
      *(ushort4*)awr[p] = f4_to_bf4(pa[p]);
      *(ushort4*)bwr[p] = f4_to_bf4(pb[p]);
    }
    // prefetch next tile (overlaps the MFMA phase below)
    if (it + 1 < INDIM / BK) {
#pragma unroll
      for (int p = 0; p < 4; ++p) {
        aptr[p] += BK; bptr[p] += BK;
        pa[p] = *(const float4*)aptr[p];
        pb[p] = *(const float4*)bptr[p];
      }
    }
    __syncthreads();   // staged data visible

#pragma unroll
    for (int kk = 0; kk < BK; kk += 32) {
      frag8 a = *(const frag8*)(ard + kk);
      frag8 b[8];
#pragma unroll
      for (int j = 0; j < 8; ++j)
        b[j] = *(const frag8*)(brd[j] + kk);
#pragma unroll
      for (int j = 0; j < 8; ++j)
        acc[j] = __builtin_amdgcn_mfma_f32_16x16x32_bf16(a, b[j], acc[j], 0, 0, 0);
    }
    __syncthreads();   // all frag reads done before next stage overwrites
  }

  // ---- epilogue: blend experts + bias, write y ----
  // C/D layout: col = lane&15 (-> out col o0+l15), row = quad*4 + r
  const int ocol = o0 + l15;
  float bgather[8];
#pragma unroll
  for (int j = 0; j < 8; ++j) bgather[j] = bias[j * OUTDIM + ocol];

  const int rbase = m0 + wave * 16 + quad * 4;
#pragma unroll
  for (int r = 0; r < 4; ++r) {
    const int b = rbase + r;
    const float* ewb = ew + b * EDIM;
    float y = 0.f;
#pragma unroll
    for (int j = 0; j < 8; ++j)
      y += ewb[j] * (acc[j][r] + bgather[j]);
    out[(size_t)b * OUTDIM + ocol] = y;
  }
}

extern "C" void kernel_launch(void* const* d_in, const int* in_sizes, int n_in,
                              void* d_out, int out_size, void* d_ws, size_t ws_size,
                              hipStream_t stream) {
  const float* x    = (const float*)d_in[0];
  const float* ew   = (const float*)d_in[1];
  const float* W    = (const float*)d_in[2];
  const float* bias = (const float*)d_in[3];
  float* out = (float*)d_out;

  // grid: 64 out-col tiles x 4 batch tiles = 256 blocks, 512 threads (8 waves)
  expert_linear_fused<<<dim3(OUTDIM / ON, 512 / TM), 512, 0, stream>>>(
      x, ew, W, bias, out);
}